// Round 2
// baseline (4030.485 us; speedup 1.0000x reference)
//
#include <hip/hip_runtime.h>
#include <hip/hip_bf16.h>
#include <math.h>

#define DIM    256
#define IDIM   64
#define HEADS  4
#define NSEQ   256
#define SEQLEN 256
#define NTOK   (NSEQ * SEQLEN)
#define EPSLN  1e-5f

// ---------- bf16 helpers (manual, on ushort) ----------
__device__ __forceinline__ float bfu_lo(unsigned int u) {
    union { unsigned int i; float f; } v; v.i = u << 16; return v.f;
}
__device__ __forceinline__ float bfu_hi(unsigned int u) {
    union { unsigned int i; float f; } v; v.i = u & 0xffff0000u; return v.f;
}
__device__ __forceinline__ float bf2f(unsigned short u) {
    union { unsigned int i; float f; } v; v.i = ((unsigned int)u) << 16; return v.f;
}
__device__ __forceinline__ unsigned short f2bf(float f) {
    union { float f; unsigned int i; } v; v.f = f;
    unsigned int x = v.i;
    unsigned int r = (x + 0x7fffu + ((x >> 16) & 1u)) >> 16;
    return (unsigned short)r;
}

// =====================================================================
// Kernel 1: LN (two param sets) + QKV projection + RoPE on q,k.
// Block = 256 threads handles 32 consecutive tokens (same sequence).
// Thread c owns output column c of Wq, and columns c (k) / c+256 (v) of Wkv.
// =====================================================================
__global__ __launch_bounds__(256) void qkv_kernel(
    const float* __restrict__ x,
    const float* __restrict__ sin_t, const float* __restrict__ cos_t,
    const float* __restrict__ ga, const float* __restrict__ ba,
    const float* __restrict__ gb, const float* __restrict__ bb,
    const float* __restrict__ Wq, const float* __restrict__ Wkv,
    unsigned short* __restrict__ qo, unsigned short* __restrict__ ko,
    unsigned short* __restrict__ vo,
    int pass)
{
    __shared__ float xs[32][DIM + 4];       // also reused for RoPE pair exchange
    __shared__ float anb[2][32][DIM + 4];   // [0]=an (q path), [1]=bn (kv path)

    const int tid  = threadIdx.x;
    const int t0   = blockIdx.x * 32;
    const int seq  = t0 >> 8;
    const int pos0 = t0 & 255;

    // ---- stage 32 x-rows ----
    for (int r = 0; r < 32; ++r) {
        int t = t0 + r;
        int row = (pass == 0) ? t : ((t & 255) * NSEQ + (t >> 8));
        xs[r][tid] = x[(size_t)row * DIM + tid];
    }
    __syncthreads();

    // ---- layernorm: 8 threads per row ----
    {
        const int r = tid >> 3, sub = tid & 7;
        float s1 = 0.f, s2 = 0.f;
        for (int m = 0; m < 32; ++m) {
            float v = xs[r][sub + 8 * m];
            s1 += v; s2 += v * v;
        }
        for (int off = 1; off < 8; off <<= 1) {
            s1 += __shfl_xor(s1, off, 64);
            s2 += __shfl_xor(s2, off, 64);
        }
        float mu   = s1 * (1.f / 256.f);
        float var  = s2 * (1.f / 256.f) - mu * mu;
        float rstd = rsqrtf(var + EPSLN);
        for (int m = 0; m < 32; ++m) {
            int d = sub + 8 * m;
            float v = (xs[r][d] - mu) * rstd;
            anb[0][r][d] = v * ga[d] + ba[d];
            anb[1][r][d] = v * gb[d] + bb[d];
        }
    }
    __syncthreads();

    // ---- GEMM: 32 rows x 768 cols, col c per thread ----
    const int c = tid;
    float aq[32], ak[32], av[32];
#pragma unroll
    for (int r = 0; r < 32; ++r) { aq[r] = 0.f; ak[r] = 0.f; av[r] = 0.f; }

    for (int k = 0; k < DIM; k += 4) {
        float wq0 = Wq[(k + 0) * DIM + c];
        float wq1 = Wq[(k + 1) * DIM + c];
        float wq2 = Wq[(k + 2) * DIM + c];
        float wq3 = Wq[(k + 3) * DIM + c];
        float wk0 = Wkv[(k + 0) * 512 + c];
        float wk1 = Wkv[(k + 1) * 512 + c];
        float wk2 = Wkv[(k + 2) * 512 + c];
        float wk3 = Wkv[(k + 3) * 512 + c];
        float wv0 = Wkv[(k + 0) * 512 + 256 + c];
        float wv1 = Wkv[(k + 1) * 512 + 256 + c];
        float wv2 = Wkv[(k + 2) * 512 + 256 + c];
        float wv3 = Wkv[(k + 3) * 512 + 256 + c];
#pragma unroll
        for (int r = 0; r < 32; ++r) {
            const float4 a4 = *reinterpret_cast<const float4*>(&anb[0][r][k]);
            const float4 b4 = *reinterpret_cast<const float4*>(&anb[1][r][k]);
            aq[r] += a4.x * wq0 + a4.y * wq1 + a4.z * wq2 + a4.w * wq3;
            ak[r] += b4.x * wk0 + b4.y * wk1 + b4.z * wk2 + b4.w * wk3;
            av[r] += b4.x * wv0 + b4.y * wv1 + b4.z * wv2 + b4.w * wv3;
        }
    }

    // ---- RoPE (full head dim) + store, layout (seq, h, pos, d) ----
    const int hd = c & 63;
    const int h  = c >> 6;
    const float sgn = (c & 1) ? 1.f : -1.f;
    const int cp = c ^ 1;
    const size_t obase = ((size_t)(seq * HEADS + h) * SEQLEN) * IDIM + hd;

    // q
    __syncthreads();
    for (int r = 0; r < 32; ++r) xs[r][c] = aq[r];
    __syncthreads();
    for (int r = 0; r < 32; ++r) {
        int pos = pos0 + r;
        float sc = sin_t[pos * IDIM + hd];
        float cc = cos_t[pos * IDIM + hd];
        float o = xs[r][c] * cc + sgn * xs[r][cp] * sc;
        qo[obase + (size_t)pos * IDIM] = f2bf(o);
    }
    __syncthreads();
    // k
    for (int r = 0; r < 32; ++r) xs[r][c] = ak[r];
    __syncthreads();
    for (int r = 0; r < 32; ++r) {
        int pos = pos0 + r;
        float sc = sin_t[pos * IDIM + hd];
        float cc = cos_t[pos * IDIM + hd];
        float o = xs[r][c] * cc + sgn * xs[r][cp] * sc;
        ko[obase + (size_t)pos * IDIM] = f2bf(o);
    }
    // v: no rope
    for (int r = 0; r < 32; ++r) {
        int pos = pos0 + r;
        vo[obase + (size_t)pos * IDIM] = f2bf(av[r]);
    }
}

// =====================================================================
// Kernel 2: attention per (seq, head). Block = 256 threads, thread = query row.
// K,V staged in LDS as f32 (128 KB). Online softmax. No 1/sqrt(d) scale.
// Output written d-major: ao[token*256 + d*4 + h].
// =====================================================================
__global__ __launch_bounds__(256) void attn_kernel(
    const unsigned short* __restrict__ qb,
    const unsigned short* __restrict__ kb,
    const unsigned short* __restrict__ vb,
    unsigned short* __restrict__ ao)
{
    __shared__ float Ks[SEQLEN][IDIM];
    __shared__ float Vs[SEQLEN][IDIM];

    const int tid = threadIdx.x;
    const int sh  = blockIdx.x;          // seq*HEADS + h
    const int seq = sh >> 2;
    const int h   = sh & 3;
    const size_t base2 = (size_t)sh * (SEQLEN * IDIM / 2);  // in uints

    const unsigned int* kg = reinterpret_cast<const unsigned int*>(kb) + base2;
    const unsigned int* vg = reinterpret_cast<const unsigned int*>(vb) + base2;
    float* Ksf = &Ks[0][0];
    float* Vsf = &Vs[0][0];
    for (int it = tid; it < SEQLEN * IDIM / 2; it += 256) {
        unsigned int u = kg[it];
        Ksf[2 * it] = bfu_lo(u); Ksf[2 * it + 1] = bfu_hi(u);
        u = vg[it];
        Vsf[2 * it] = bfu_lo(u); Vsf[2 * it + 1] = bfu_hi(u);
    }

    // load this thread's q row (64 bf16 = 32 uints)
    float qr[IDIM];
    {
        const uint4* qg = reinterpret_cast<const uint4*>(
            reinterpret_cast<const unsigned int*>(qb) + base2 + (size_t)tid * (IDIM / 2));
#pragma unroll
        for (int i4 = 0; i4 < 8; ++i4) {
            uint4 u = qg[i4];
            qr[8 * i4 + 0] = bfu_lo(u.x); qr[8 * i4 + 1] = bfu_hi(u.x);
            qr[8 * i4 + 2] = bfu_lo(u.y); qr[8 * i4 + 3] = bfu_hi(u.y);
            qr[8 * i4 + 4] = bfu_lo(u.z); qr[8 * i4 + 5] = bfu_hi(u.z);
            qr[8 * i4 + 6] = bfu_lo(u.w); qr[8 * i4 + 7] = bfu_hi(u.w);
        }
    }
    __syncthreads();

    float m = -1e30f, l = 0.f;
    float o[IDIM];
#pragma unroll
    for (int d = 0; d < IDIM; ++d) o[d] = 0.f;

    for (int kk = 0; kk < SEQLEN; ++kk) {
        float dot = 0.f;
#pragma unroll
        for (int d4 = 0; d4 < IDIM / 4; ++d4) {
            const float4 k4 = *reinterpret_cast<const float4*>(&Ks[kk][d4 * 4]);
            dot += qr[4 * d4 + 0] * k4.x + qr[4 * d4 + 1] * k4.y
                 + qr[4 * d4 + 2] * k4.z + qr[4 * d4 + 3] * k4.w;
        }
        if (dot > m) {
            float f = __expf(m - dot);
            l *= f;
#pragma unroll
            for (int d = 0; d < IDIM; ++d) o[d] *= f;
            m = dot;
        }
        float p = __expf(dot - m);
        l += p;
#pragma unroll
        for (int d4 = 0; d4 < IDIM / 4; ++d4) {
            const float4 v4 = *reinterpret_cast<const float4*>(&Vs[kk][d4 * 4]);
            o[4 * d4 + 0] += p * v4.x;
            o[4 * d4 + 1] += p * v4.y;
            o[4 * d4 + 2] += p * v4.z;
            o[4 * d4 + 3] += p * v4.w;
        }
    }

    const float inv = 1.f / l;
    const size_t ob = ((size_t)(seq * SEQLEN + tid)) * DIM + h;
#pragma unroll
    for (int d = 0; d < IDIM; ++d)
        ao[ob + (size_t)d * HEADS] = f2bf(o[d] * inv);
}

// =====================================================================
// Kernel 3: out = (pass0 ? x + 0.5*elu(ao@Wo+bo) : out + 0.5*elu(ao@Wo+bo))
// Block = 256 threads handles 32 tokens; thread c owns column c of Wo.
// =====================================================================
__global__ __launch_bounds__(256) void proj_kernel(
    const float* __restrict__ x,
    const unsigned short* __restrict__ ao,
    const float* __restrict__ Wo, const float* __restrict__ bo,
    float* __restrict__ out, int pass)
{
    __shared__ float as[32][DIM + 4];

    const int tid = threadIdx.x;
    const int t0  = blockIdx.x * 32;

    for (int r = 0; r < 32; ++r)
        as[r][tid] = bf2f(ao[(size_t)(t0 + r) * DIM + tid]);
    __syncthreads();

    const int c = tid;
    float acc[32];
#pragma unroll
    for (int r = 0; r < 32; ++r) acc[r] = 0.f;

    for (int k = 0; k < DIM; k += 4) {
        float w0 = Wo[(k + 0) * DIM + c];
        float w1 = Wo[(k + 1) * DIM + c];
        float w2 = Wo[(k + 2) * DIM + c];
        float w3 = Wo[(k + 3) * DIM + c];
#pragma unroll
        for (int r = 0; r < 32; ++r) {
            const float4 a4 = *reinterpret_cast<const float4*>(&as[r][k]);
            acc[r] += a4.x * w0 + a4.y * w1 + a4.z * w2 + a4.w * w3;
        }
    }

    const float bc = bo[c];
    for (int r = 0; r < 32; ++r) {
        int t = t0 + r;
        float y = acc[r] + bc;
        float e = (y > 0.f) ? y : (__expf(y) - 1.f);
        size_t row = (pass == 0) ? (size_t)t
                                 : ((size_t)(t & 255) * NSEQ + (t >> 8));
        size_t idx = row * DIM + c;
        if (pass == 0) out[idx] = x[idx] + 0.5f * e;
        else           out[idx] += 0.5f * e;
    }
}

// =====================================================================
extern "C" void kernel_launch(void* const* d_in, const int* in_sizes, int n_in,
                              void* d_out, int out_size, void* d_ws, size_t ws_size,
                              hipStream_t stream) {
    const float* x     = (const float*)d_in[0];
    const float* sin_i = (const float*)d_in[1];
    const float* cos_i = (const float*)d_in[2];
    const float* sin_j = (const float*)d_in[3];
    const float* cos_j = (const float*)d_in[4];
    const float* gia   = (const float*)d_in[5];
    const float* bia   = (const float*)d_in[6];
    const float* gib   = (const float*)d_in[7];
    const float* bib   = (const float*)d_in[8];
    const float* Wq_i  = (const float*)d_in[9];
    const float* Wkv_i = (const float*)d_in[10];
    const float* Wo_i  = (const float*)d_in[11];
    const float* bo_i  = (const float*)d_in[12];
    const float* gja   = (const float*)d_in[13];
    const float* bja   = (const float*)d_in[14];
    const float* gjb   = (const float*)d_in[15];
    const float* bjb   = (const float*)d_in[16];
    const float* Wq_j  = (const float*)d_in[17];
    const float* Wkv_j = (const float*)d_in[18];
    const float* Wo_j  = (const float*)d_in[19];
    const float* bo_j  = (const float*)d_in[20];

    float* out = (float*)d_out;

    unsigned short* q  = (unsigned short*)d_ws;
    unsigned short* k  = q + (size_t)NTOK * DIM;
    unsigned short* v  = k + (size_t)NTOK * DIM;
    unsigned short* ao = v + (size_t)NTOK * DIM;

    // ---- pass i (rows: seq = i, pos = j) ----
    qkv_kernel<<<dim3(NTOK / 32), dim3(256), 0, stream>>>(
        x, sin_i, cos_i, gia, bia, gib, bib, Wq_i, Wkv_i, q, k, v, 0);
    attn_kernel<<<dim3(NSEQ * HEADS), dim3(256), 0, stream>>>(q, k, v, ao);
    proj_kernel<<<dim3(NTOK / 32), dim3(256), 0, stream>>>(
        x, ao, Wo_i, bo_i, out, 0);

    // ---- pass j (rows: seq = j, pos = i) ----
    qkv_kernel<<<dim3(NTOK / 32), dim3(256), 0, stream>>>(
        x, sin_j, cos_j, gja, bja, gjb, bjb, Wq_j, Wkv_j, q, k, v, 1);
    attn_kernel<<<dim3(NSEQ * HEADS), dim3(256), 0, stream>>>(q, k, v, ao);
    proj_kernel<<<dim3(NTOK / 32), dim3(256), 0, stream>>>(
        x, ao, Wo_j, bo_j, out, 1);
}

// Round 5
// 864.098 us; speedup vs baseline: 4.6644x; 4.6644x over previous
//
#include <hip/hip_runtime.h>
#include <math.h>

#define DIM    256
#define IDIM   64
#define HEADS  4
#define NSEQ   256
#define SEQLEN 256
#define NTOK   (NSEQ * SEQLEN)
#define EPSLN  1e-5f

typedef __attribute__((ext_vector_type(8))) short bf16x8s;
typedef __attribute__((ext_vector_type(4))) float f32x4;

union BF8 { bf16x8s v; unsigned short u[8]; };

__device__ __forceinline__ float bf2f(unsigned short u) {
    union { unsigned int i; float f; } v; v.i = ((unsigned int)u) << 16; return v.f;
}
__device__ __forceinline__ unsigned short f2bf(float f) {
    union { float f; unsigned int i; } v; v.f = f;
    unsigned int x = v.i;
    return (unsigned short)((x + 0x7fffu + ((x >> 16) & 1u)) >> 16);
}

// Packed weights: 4 matrices (wq, wk, wv, wo), each [16 nt][8 kt][64 lanes] x bf16x8
__device__ bf16x8s g_wpk[4][8192];

// =====================================================================
// Pack weights into B-fragment layout: lane l holds B[k=kt*32+8*(l>>4)+j][n=nt*16+(l&15)]
// perm: for Wo, packed k index k' is h-major (h*64+d); source row is d-major (d*4+h).
// =====================================================================
__global__ __launch_bounds__(256) void wpack_kernel(
    const float* __restrict__ W, int ldw, int col0, int perm, int widx)
{
    const int gtile = blockIdx.x * 4 + (threadIdx.x >> 6);   // nt*8+kt, 128 tiles
    const int l = threadIdx.x & 63;
    const int nt = gtile >> 3, kt = gtile & 7;
    const int n = nt * 16 + (l & 15);
    const int k0 = kt * 32 + (l >> 4) * 8;
    BF8 o;
#pragma unroll
    for (int j = 0; j < 8; ++j) {
        int k = k0 + j;
        int src = perm ? ((k & 63) * 4 + (k >> 6)) : k;
        o.u[j] = f2bf(W[(size_t)src * ldw + col0 + n]);
    }
    g_wpk[widx][(size_t)gtile * 64 + l] = o.v;
}

// =====================================================================
// Fused LN + QKV GEMM (f32 activations, hi+lo bf16 MFMA) + RoPE + repack.
// Block = 32 tokens (one seq), computes all 768 output cols.
// 4 waves; wave w owns n-tiles [w*12, w*12+12)  (192 cols).
// LDS: one f32 buffer; phase 1 = xn[32][264] + g[4][256]; phase 2 = C[32][776].
// =====================================================================
#define XLD  264
#define GOFF (32 * XLD)           // 8448
#define CLD  776

__global__ __launch_bounds__(256) void lnqkv_kernel(
    const float* __restrict__ x,
    const float* __restrict__ sin_t, const float* __restrict__ cos_t,
    const float* __restrict__ ga, const float* __restrict__ ba,
    const float* __restrict__ gb, const float* __restrict__ bb,
    bf16x8s* __restrict__ qo, bf16x8s* __restrict__ ko, bf16x8s* __restrict__ vo,
    int pass)
{
    __shared__ float smf[32 * CLD];   // 99,328 B

    const int tid = threadIdx.x;
    const int l = tid & 63, w = tid >> 6;
    const int lr = l & 15, lk = l >> 4;
    const int t0 = blockIdx.x * 32;
    const int seq = t0 >> 8;
    const int pos0 = t0 & 255;

    // ---- stage x rows + LN params ----
    for (int r = 0; r < 32; ++r) {
        int t = t0 + r;
        int row = (pass == 0) ? t : ((t & 255) * NSEQ + (t >> 8));
        smf[r * XLD + tid] = x[(size_t)row * DIM + tid];
    }
    smf[GOFF + 0 * 256 + tid] = ga[tid];
    smf[GOFF + 1 * 256 + tid] = ba[tid];
    smf[GOFF + 2 * 256 + tid] = gb[tid];
    smf[GOFF + 3 * 256 + tid] = bb[tid];
    __syncthreads();

    // ---- LN stats (8 threads/row), normalize in place (no gamma/beta) ----
    {
        const int r = tid >> 3, sub = tid & 7;
        float s1 = 0.f, s2 = 0.f;
        for (int m = 0; m < 32; ++m) { float v = smf[r * XLD + sub + 8 * m]; s1 += v; s2 += v * v; }
        for (int off = 1; off < 8; off <<= 1) {
            s1 += __shfl_xor(s1, off, 64);
            s2 += __shfl_xor(s2, off, 64);
        }
        float mu = s1 * (1.f / 256.f);
        float var = s2 * (1.f / 256.f) - mu * mu;
        float rstd = rsqrtf(var + EPSLN);
        for (int m = 0; m < 32; ++m) {
            int d = sub + 8 * m;
            smf[r * XLD + d] = (smf[r * XLD + d] - mu) * rstd;
        }
    }
    __syncthreads();

    // ---- K-loop: acc[2 m-frags][12 n-frags], hi+lo A ----
    f32x4 acc[2][12];
#pragma unroll
    for (int mf = 0; mf < 2; ++mf)
#pragma unroll
        for (int nf = 0; nf < 12; ++nf) { f32x4 z = {0.f, 0.f, 0.f, 0.f}; acc[mf][nf] = z; }

    const int nt0 = w * 12;
    const bool needA = (nt0 < 16);          // any q cols in this wave's strip
    const bool needB = (nt0 + 11 >= 16);    // any k/v cols

    for (int ks = 0; ks < 8; ++ks) {
        const int c0 = ks * 32 + lk * 8;
        float gav[8], bav[8], gbv[8], bbv[8];
#pragma unroll
        for (int j = 0; j < 8; ++j) {
            gav[j] = smf[GOFF + 0 * 256 + c0 + j];
            bav[j] = smf[GOFF + 1 * 256 + c0 + j];
            gbv[j] = smf[GOFF + 2 * 256 + c0 + j];
            bbv[j] = smf[GOFF + 3 * 256 + c0 + j];
        }
        BF8 ahA[2], alA[2], ahB[2], alB[2];
#pragma unroll
        for (int mf = 0; mf < 2; ++mf) {
            const float* xr = &smf[(mf * 16 + lr) * XLD + c0];
            float xv[8];
#pragma unroll
            for (int j = 0; j < 8; ++j) xv[j] = xr[j];
            if (needA) {
#pragma unroll
                for (int j = 0; j < 8; ++j) {
                    float a = xv[j] * gav[j] + bav[j];
                    unsigned short hi = f2bf(a);
                    ahA[mf].u[j] = hi;
                    alA[mf].u[j] = f2bf(a - bf2f(hi));
                }
            }
            if (needB) {
#pragma unroll
                for (int j = 0; j < 8; ++j) {
                    float a = xv[j] * gbv[j] + bbv[j];
                    unsigned short hi = f2bf(a);
                    ahB[mf].u[j] = hi;
                    alB[mf].u[j] = f2bf(a - bf2f(hi));
                }
            }
        }
#pragma unroll
        for (int nf = 0; nf < 12; ++nf) {
            const int ntg = nt0 + nf;      // wave-uniform
            const bf16x8s b = g_wpk[ntg >> 4][((size_t)((ntg & 15) * 8 + ks)) * 64 + l];
            if (ntg < 16) {
#pragma unroll
                for (int mf = 0; mf < 2; ++mf) {
                    acc[mf][nf] = __builtin_amdgcn_mfma_f32_16x16x32_bf16(alA[mf].v, b, acc[mf][nf], 0, 0, 0);
                    acc[mf][nf] = __builtin_amdgcn_mfma_f32_16x16x32_bf16(ahA[mf].v, b, acc[mf][nf], 0, 0, 0);
                }
            } else {
#pragma unroll
                for (int mf = 0; mf < 2; ++mf) {
                    acc[mf][nf] = __builtin_amdgcn_mfma_f32_16x16x32_bf16(alB[mf].v, b, acc[mf][nf], 0, 0, 0);
                    acc[mf][nf] = __builtin_amdgcn_mfma_f32_16x16x32_bf16(ahB[mf].v, b, acc[mf][nf], 0, 0, 0);
                }
            }
        }
    }
    __syncthreads();   // xn/g regions dead from here

    // ---- write C (f32), rows=tokens(32), cols=768 ----
#pragma unroll
    for (int mf = 0; mf < 2; ++mf)
#pragma unroll
        for (int nf = 0; nf < 12; ++nf)
#pragma unroll
            for (int r = 0; r < 4; ++r)
                smf[(mf * 16 + lk * 4 + r) * CLD + (nt0 + nf) * 16 + lr] = acc[mf][nf][r];
    __syncthreads();

    // ---- epilogue: 48 tiles (16 q + 16 k + 16 v) ----
    for (int it = 0; it < 12; ++it) {
        int tile = w + 4 * it;
        if (tile < 32) {
            // q (tile<16) or k: RoPE + pack-A
            int isk = tile >> 4;
            int tt = tile & 15;
            int h = tt >> 2, mt = (tt >> 1) & 1, ktd = tt & 1;
            int row = mt * 16 + lr;
            int pos = pos0 + row;
            int d0 = ktd * 32 + lk * 8;
            const float* src = &smf[row * CLD + isk * 256 + h * 64 + d0];
            BF8 o;
#pragma unroll
            for (int p2 = 0; p2 < 4; ++p2) {
                float cs = cos_t[pos * IDIM + d0 + 2 * p2];
                float sn = sin_t[pos * IDIM + d0 + 2 * p2];
                float e = src[2 * p2], od = src[2 * p2 + 1];
                o.u[2 * p2]     = f2bf(e * cs - od * sn);
                o.u[2 * p2 + 1] = f2bf(od * cs + e * sn);
            }
            int sh = seq * 4 + h;
            int mtg = (pos0 >> 4) + mt;
            bf16x8s* dst = isk ? ko : qo;
            dst[((size_t)sh * 32 + mtg * 2 + ktd) * 64 + l] = o.v;
        } else {
            // v: pack-B over [kpos][d]
            int tt = tile - 32;
            int h = tt >> 2, ntd = tt & 3;
            BF8 o;
#pragma unroll
            for (int j = 0; j < 8; ++j)
                o.u[j] = f2bf(smf[(lk * 8 + j) * CLD + 512 + h * 64 + ntd * 16 + lr]);
            int sh = seq * 4 + h;
            int ktg = pos0 >> 5;
            vo[((size_t)sh * 32 + ktg * 4 + ntd) * 64 + l] = o.v;
        }
    }
}

// =====================================================================
// Attention: block = (seq,head). 4 waves x 64 q-rows. Flash over 4 key-tiles of 64.
// q/k packed-A over [pos][d]; v packed-B over [kpos][d].
// Output packed-A over [token][h*64+d] (h-major; Wo rows are permuted to match).
// =====================================================================
__global__ __launch_bounds__(256) void attn_kernel(
    const bf16x8s* __restrict__ qpk, const bf16x8s* __restrict__ kpk,
    const bf16x8s* __restrict__ vpk, bf16x8s* __restrict__ opk)
{
    __shared__ float P[4][64][66];
    const int tid = threadIdx.x, l = tid & 63, w = tid >> 6;
    const int sh = blockIdx.x;
    const size_t base = (size_t)sh * 32 * 64;   // 32 tiles of 64 frags per sh

    bf16x8s qf[4][2];
#pragma unroll
    for (int mf = 0; mf < 4; ++mf)
#pragma unroll
        for (int kt = 0; kt < 2; ++kt)
            qf[mf][kt] = qpk[base + ((size_t)((w * 4 + mf) * 2 + kt)) * 64 + l];

    f32x4 O[4][4];
    float mrun[4][4], lrun[4][4];
#pragma unroll
    for (int mf = 0; mf < 4; ++mf)
#pragma unroll
        for (int nf = 0; nf < 4; ++nf) { f32x4 z = {0.f, 0.f, 0.f, 0.f}; O[mf][nf] = z; }
#pragma unroll
    for (int mf = 0; mf < 4; ++mf)
#pragma unroll
        for (int r = 0; r < 4; ++r) { mrun[mf][r] = -1e30f; lrun[mf][r] = 0.f; }

    for (int ktk = 0; ktk < 4; ++ktk) {
        f32x4 S[4][4];
#pragma unroll
        for (int mf = 0; mf < 4; ++mf)
#pragma unroll
            for (int nf = 0; nf < 4; ++nf) { f32x4 z = {0.f, 0.f, 0.f, 0.f}; S[mf][nf] = z; }
#pragma unroll
        for (int ks = 0; ks < 2; ++ks) {
            bf16x8s kf[4];
#pragma unroll
            for (int nf = 0; nf < 4; ++nf)
                kf[nf] = kpk[base + ((size_t)((ktk * 4 + nf) * 2 + ks)) * 64 + l];
#pragma unroll
            for (int mf = 0; mf < 4; ++mf)
#pragma unroll
                for (int nf = 0; nf < 4; ++nf)
                    S[mf][nf] = __builtin_amdgcn_mfma_f32_16x16x32_bf16(qf[mf][ks], kf[nf], S[mf][nf], 0, 0, 0);
        }
        // online softmax per row
#pragma unroll
        for (int mf = 0; mf < 4; ++mf) {
#pragma unroll
            for (int r = 0; r < 4; ++r) {
                float mt_ = fmaxf(fmaxf(S[mf][0][r], S[mf][1][r]), fmaxf(S[mf][2][r], S[mf][3][r]));
                for (int off = 1; off < 16; off <<= 1) mt_ = fmaxf(mt_, __shfl_xor(mt_, off, 64));
                float mnew = fmaxf(mrun[mf][r], mt_);
                float sc = __expf(mrun[mf][r] - mnew);
#pragma unroll
                for (int nf = 0; nf < 4; ++nf) O[mf][nf][r] *= sc;
                float ps = 0.f;
#pragma unroll
                for (int nf = 0; nf < 4; ++nf) {
                    float pp = __expf(S[mf][nf][r] - mnew);
                    S[mf][nf][r] = pp;
                    ps += pp;
                }
                for (int off = 1; off < 16; off <<= 1) ps += __shfl_xor(ps, off, 64);
                lrun[mf][r] = lrun[mf][r] * sc + ps;
                mrun[mf][r] = mnew;
            }
        }
#pragma unroll
        for (int mf = 0; mf < 4; ++mf)
#pragma unroll
            for (int nf = 0; nf < 4; ++nf)
#pragma unroll
                for (int r = 0; r < 4; ++r)
                    P[w][mf * 16 + (l >> 4) * 4 + r][nf * 16 + (l & 15)] = S[mf][nf][r];
        __syncthreads();
#pragma unroll
        for (int ks = 0; ks < 2; ++ks) {
            bf16x8s vf[4];
#pragma unroll
            for (int nf = 0; nf < 4; ++nf)
                vf[nf] = vpk[base + ((size_t)((ktk * 2 + ks) * 4 + nf)) * 64 + l];
#pragma unroll
            for (int mf = 0; mf < 4; ++mf) {
                BF8 pa;
#pragma unroll
                for (int j = 0; j < 8; ++j)
                    pa.u[j] = f2bf(P[w][mf * 16 + (l & 15)][ks * 32 + (l >> 4) * 8 + j]);
#pragma unroll
                for (int nf = 0; nf < 4; ++nf)
                    O[mf][nf] = __builtin_amdgcn_mfma_f32_16x16x32_bf16(pa.v, vf[nf], O[mf][nf], 0, 0, 0);
            }
        }
        __syncthreads();
    }

    // normalize, round-trip LDS, pack-A into opk at h-major cols
#pragma unroll
    for (int mf = 0; mf < 4; ++mf) {
#pragma unroll
        for (int r = 0; r < 4; ++r) {
            float inv = 1.f / lrun[mf][r];
#pragma unroll
            for (int nf = 0; nf < 4; ++nf)
                P[w][mf * 16 + (l >> 4) * 4 + r][nf * 16 + (l & 15)] = O[mf][nf][r] * inv;
        }
    }
    __syncthreads();
    const int seq = sh >> 2, h = sh & 3;
#pragma unroll
    for (int mf = 0; mf < 4; ++mf)
#pragma unroll
        for (int ktd = 0; ktd < 2; ++ktd) {
            BF8 o;
#pragma unroll
            for (int j = 0; j < 8; ++j)
                o.u[j] = f2bf(P[w][mf * 16 + (l & 15)][ktd * 32 + (l >> 4) * 8 + j]);
            size_t mtg = (size_t)seq * 16 + w * 4 + mf;
            opk[(mtg * 8 + h * 2 + ktd) * 64 + l] = o.v;
        }
}

// =====================================================================
// Proj GEMM: A = o_pk, B = g_wpk[3] (row-permuted Wo). Epilogue: bias+ELU+residual.
// =====================================================================
__device__ __forceinline__ void gemm_core(
    const bf16x8s* __restrict__ A, const bf16x8s* __restrict__ B,
    int mt0, int nt0, int l, f32x4 acc[4][4])
{
#pragma unroll
    for (int mf = 0; mf < 4; ++mf)
#pragma unroll
        for (int nf = 0; nf < 4; ++nf) { f32x4 z = {0.f, 0.f, 0.f, 0.f}; acc[mf][nf] = z; }
#pragma unroll
    for (int ks = 0; ks < 8; ++ks) {
        bf16x8s a[4], b[4];
#pragma unroll
        for (int mf = 0; mf < 4; ++mf) a[mf] = A[((size_t)(mt0 + mf) * 8 + ks) * 64 + l];
#pragma unroll
        for (int nf = 0; nf < 4; ++nf) b[nf] = B[((size_t)(nt0 + nf) * 8 + ks) * 64 + l];
#pragma unroll
        for (int mf = 0; mf < 4; ++mf)
#pragma unroll
            for (int nf = 0; nf < 4; ++nf)
                acc[mf][nf] = __builtin_amdgcn_mfma_f32_16x16x32_bf16(a[mf], b[nf], acc[mf][nf], 0, 0, 0);
    }
}

__global__ __launch_bounds__(256) void gemm_proj_kernel(
    const bf16x8s* __restrict__ A,
    const float* __restrict__ x, const float* __restrict__ bo,
    float* __restrict__ out, int pass)
{
    __shared__ float Cf[128][129];
    const int tid = threadIdx.x;
    const int l = tid & 63, w = tid >> 6;
    const int wm = w >> 1, wn = w & 1;
    const int mb = blockIdx.x, nb = blockIdx.y;

    f32x4 acc[4][4];
    gemm_core(A, g_wpk[3], mb * 8 + wm * 4, nb * 8 + wn * 4, l, acc);

#pragma unroll
    for (int mf = 0; mf < 4; ++mf)
#pragma unroll
        for (int nf = 0; nf < 4; ++nf)
#pragma unroll
            for (int r = 0; r < 4; ++r)
                Cf[wm * 64 + mf * 16 + (l >> 4) * 4 + r][wn * 64 + nf * 16 + (l & 15)] =
                    acc[mf][nf][r];
    __syncthreads();

    const int row = tid >> 1;
    const int cc0 = (tid & 1) * 64;
    const int tok = mb * 128 + row;
    const size_t prow = (pass == 0) ? (size_t)tok
                                    : ((size_t)(tok & 255) * NSEQ + (tok >> 8));
    const size_t gb = prow * DIM + nb * 128 + cc0;
#pragma unroll
    for (int qq = 0; qq < 16; ++qq) {
        float4 r4;
        float* yp = &Cf[row][cc0 + qq * 4];
        const float4 b4 = *reinterpret_cast<const float4*>(&bo[nb * 128 + cc0 + qq * 4]);
        float y0 = yp[0] + b4.x, y1 = yp[1] + b4.y, y2 = yp[2] + b4.z, y3 = yp[3] + b4.w;
        r4.x = 0.5f * (y0 > 0.f ? y0 : expm1f(y0));
        r4.y = 0.5f * (y1 > 0.f ? y1 : expm1f(y1));
        r4.z = 0.5f * (y2 > 0.f ? y2 : expm1f(y2));
        r4.w = 0.5f * (y3 > 0.f ? y3 : expm1f(y3));
        if (pass == 0) {
            const float4 x4 = *reinterpret_cast<const float4*>(&x[gb + qq * 4]);
            r4.x += x4.x; r4.y += x4.y; r4.z += x4.z; r4.w += x4.w;
            *reinterpret_cast<float4*>(&out[gb + qq * 4]) = r4;
        } else {
            float4* op = reinterpret_cast<float4*>(&out[gb + qq * 4]);
            float4 o4 = *op;
            o4.x += r4.x; o4.y += r4.y; o4.z += r4.z; o4.w += r4.w;
            *op = o4;
        }
    }
}

// =====================================================================
extern "C" void kernel_launch(void* const* d_in, const int* in_sizes, int n_in,
                              void* d_out, int out_size, void* d_ws, size_t ws_size,
                              hipStream_t stream) {
    const float* x     = (const float*)d_in[0];
    const float* sin_i = (const float*)d_in[1];
    const float* cos_i = (const float*)d_in[2];
    const float* sin_j = (const float*)d_in[3];
    const float* cos_j = (const float*)d_in[4];
    const float* gia   = (const float*)d_in[5];
    const float* bia   = (const float*)d_in[6];
    const float* gib   = (const float*)d_in[7];
    const float* bib   = (const float*)d_in[8];
    const float* Wq_i  = (const float*)d_in[9];
    const float* Wkv_i = (const float*)d_in[10];
    const float* Wo_i  = (const float*)d_in[11];
    const float* bo_i  = (const float*)d_in[12];
    const float* gja   = (const float*)d_in[13];
    const float* bja   = (const float*)d_in[14];
    const float* gjb   = (const float*)d_in[15];
    const float* bjb   = (const float*)d_in[16];
    const float* Wq_j  = (const float*)d_in[17];
    const float* Wkv_j = (const float*)d_in[18];
    const float* Wo_j  = (const float*)d_in[19];
    const float* bo_j  = (const float*)d_in[20];

    float* out = (float*)d_out;

    char* base = (char*)d_ws;
    const size_t MB32 = 33554432;
    bf16x8s* buf0 = (bf16x8s*)(base);             // v
    bf16x8s* buf1 = (bf16x8s*)(base + MB32);      // o
    bf16x8s* buf2 = (bf16x8s*)(base + 2 * MB32);  // q
    bf16x8s* buf3 = (bf16x8s*)(base + 3 * MB32);  // k

    for (int pass = 0; pass < 2; ++pass) {
        const float* sin_t = pass ? sin_j : sin_i;
        const float* cos_t = pass ? cos_j : cos_i;
        const float* ga = pass ? gja : gia;  const float* ba = pass ? bja : bia;
        const float* gb = pass ? gjb : gib;  const float* bb = pass ? bjb : bib;
        const float* Wq = pass ? Wq_j : Wq_i;
        const float* Wkv = pass ? Wkv_j : Wkv_i;
        const float* Wo = pass ? Wo_j : Wo_i;
        const float* bo = pass ? bo_j : bo_i;

        wpack_kernel<<<32, 256, 0, stream>>>(Wq, 256, 0, 0, 0);
        wpack_kernel<<<32, 256, 0, stream>>>(Wkv, 512, 0, 0, 1);
        wpack_kernel<<<32, 256, 0, stream>>>(Wkv, 512, 256, 0, 2);
        wpack_kernel<<<32, 256, 0, stream>>>(Wo, 256, 0, 1, 3);

        // fused LN + QKV + RoPE + repack: q->buf2, k->buf3, v->buf0
        lnqkv_kernel<<<2048, 256, 0, stream>>>(
            x, sin_t, cos_t, ga, ba, gb, bb, buf2, buf3, buf0, pass);
        // attn: q,k,v -> o (buf1)
        attn_kernel<<<1024, 256, 0, stream>>>(buf2, buf3, buf0, buf1);
        // proj + residual
        gemm_proj_kernel<<<dim3(512, 2), 256, 0, stream>>>(buf1, x, bo, out, pass);
    }
}